// Round 14
// baseline (285.749 us; speedup 1.0000x reference)
//
#include <hip/hip_runtime.h>
#include <cstddef>
#include <cstdint>

#define N_     2048
#define H_     32
#define NEGF   (-1.0e30f)
#define LOG2E  1.4426950408889634f
#define C1F    (0.17677669529663687f * 1.4426950408889634f)   // (1/sqrt(32))*log2e
#define DEFER  16.0f
#define NCHUNK 32
#define CLEN   64             // N_/NCHUNK
#define NRTOT  8192           // B*N

#define AS1 __attribute__((address_space(1)))
#define AS3 __attribute__((address_space(3)))

typedef float v2f __attribute__((ext_vector_type(2)));

__device__ __forceinline__ float exp2_fast(float x) {
    float r;
    asm("v_exp_f32 %0, %1" : "=v"(r) : "v"(x));
    return r;
}

// RNE float -> bf16
__device__ __forceinline__ unsigned short f2bf(float x) {
    unsigned u = __builtin_bit_cast(unsigned, x);
    return (unsigned short)((u + 0x7FFFu + ((u >> 16) & 1u)) >> 16);
}

// unpack a u32 holding bf16 pair (lo = elem 2w, hi = elem 2w+1) -> v2f
__device__ __forceinline__ v2f bf2(unsigned u) {
    v2f r;
    r.x = __builtin_bit_cast(float, u << 16);
    r.y = __builtin_bit_cast(float, u & 0xffff0000u);
    return r;
}

// ---------------------------------------------------------------- adj -> bitmask
__global__ __launch_bounds__(256) void k_adjmask(const int* __restrict__ adj,
                                                 unsigned long long* __restrict__ mask) {
    size_t idx = (size_t)blockIdx.x * 256 + threadIdx.x;     // over B*N*N
    unsigned long long m = __ballot(adj[idx] != 0);
    if ((threadIdx.x & 63) == 0) mask[idx >> 6] = m;
}

// ---------------------------------------------------------------- fused h-init + layer-0 qkv (k/v as bf16)
__global__ __launch_bounds__(256) void k_init_qkv(const float* __restrict__ feats,
                                                  const float* __restrict__ W_in,
                                                  const float* __restrict__ Wq,
                                                  const float* __restrict__ Wk,
                                                  const float* __restrict__ Wv,
                                                  float* __restrict__ h,
                                                  float* __restrict__ q,
                                                  unsigned short* __restrict__ kb,
                                                  unsigned short* __restrict__ vb) {
    __shared__ float hs[8][33];
    int t = threadIdx.x;
    int rl = t >> 5, c = t & 31;
    int row = blockIdx.x * 8 + rl;
    float f0 = feats[row * 3 + 0], f1 = feats[row * 3 + 1], f2 = feats[row * 3 + 2];
    float hv = f0 * W_in[c] + f1 * W_in[32 + c] + f2 * W_in[64 + c];
    hs[rl][c] = hv;
    h[(row << 5) + c] = hv;
    __syncthreads();
    float aq = 0.f, ak = 0.f, av = 0.f;
#pragma unroll
    for (int d = 0; d < 32; ++d) {
        float hd = hs[rl][d];
        aq += hd * Wq[(d << 5) + c];
        ak += hd * Wk[(d << 5) + c];
        av += hd * Wv[(d << 5) + c];
    }
    q[(row << 5) + c]  = aq;
    kb[(row << 5) + c] = f2bf(ak);
    vb[(row << 5) + c] = f2bf(av);
}

// ---------------------------------------------------------------- attention core
// 2 rows/lane, 512 rows/block, CLEN=64 j-chunk in LDS as bf16 (wave-uniform
// broadcast reads: 9 b128/jj instead of 17 -> 72 B LDS-bus bytes per pair).
// Unpack bf16->v2f in registers; all arithmetic/accumulation fp32.
__global__ __launch_bounds__(256) void k_attn(const float* __restrict__ qg,
                                              const unsigned short* __restrict__ kbg,
                                              const unsigned short* __restrict__ vbg,
                                              const float* __restrict__ xin,
                                              const unsigned long long* __restrict__ maskg,
                                              float* __restrict__ pm,
                                              float* __restrict__ ps,
                                              float* __restrict__ pacc) {
    __shared__ __attribute__((aligned(16))) unsigned short kb_lds[CLEN * 32];
    __shared__ __attribute__((aligned(16))) unsigned short vb_lds[CLEN * 32];
    __shared__ __attribute__((aligned(16))) float x_lds[CLEN * 4];

    const int t    = threadIdx.x;
    const int w    = t >> 6, lane = t & 63;
    const int rg   = blockIdx.x >> 5;        // 16 row-groups of 512 rows
    const int cid  = blockIdx.x & 31;        // 32 chunks
    const int b    = rg >> 2;
    const int bN   = b << 11;
    const int j0   = cid << 6;
    const int r0   = (rg << 9) + (w << 6) + lane;
    const int r1   = r0 + 256;

    // ---- stage K/V chunk (bf16: 64 rows x 64B = 4KB each; one 16B load/thread)
    {
        const unsigned short* kbase = kbg + (((size_t)(bN + j0)) << 5) + (t << 3);
        const unsigned short* vbase = vbg + (((size_t)(bN + j0)) << 5) + (t << 3);
        __builtin_amdgcn_global_load_lds((const AS1 void*)kbase,
            (AS3 void*)((char*)kb_lds + (t << 4)), 16, 0, 0);
        __builtin_amdgcn_global_load_lds((const AS1 void*)vbase,
            (AS3 void*)((char*)vb_lds + (t << 4)), 16, 0, 0);
    }
    if (t < CLEN) {
        const float* xp = xin + ((size_t)(bN + j0 + t)) * 3;
        float4 xv; xv.x = xp[0]; xv.y = xp[1]; xv.z = xp[2]; xv.w = 0.f;
        *(float4*)(x_lds + (t << 2)) = xv;
    }

    // ---- per-lane 2-row state (packed pairs)
    v2f q2a[16], q2b[16];
#pragma unroll
    for (int d = 0; d < 32; d += 4) {
        float4 a = *(const float4*)(qg + (((size_t)r0) << 5) + d);
        v2f lo; lo.x = a.x * C1F; lo.y = a.y * C1F;
        v2f hi; hi.x = a.z * C1F; hi.y = a.w * C1F;
        q2a[d >> 1] = lo; q2a[(d >> 1) + 1] = hi;
        float4 bb = *(const float4*)(qg + (((size_t)r1) << 5) + d);
        v2f lo2; lo2.x = bb.x * C1F; lo2.y = bb.y * C1F;
        v2f hi2; hi2.x = bb.z * C1F; hi2.y = bb.w * C1F;
        q2b[d >> 1] = lo2; q2b[(d >> 1) + 1] = hi2;
    }
    const float xa0 = xin[r0 * 3 + 0], xa1 = xin[r0 * 3 + 1], xa2 = xin[r0 * 3 + 2];
    const float xb0 = xin[r1 * 3 + 0], xb1 = xin[r1 * 3 + 1], xb2 = xin[r1 * 3 + 2];
    unsigned long long mwa = maskg[((size_t)r0 << 5) + cid];
    unsigned long long mwb = maskg[((size_t)r1 << 5) + cid];

    v2f acc2a[16], acc2b[16];
#pragma unroll
    for (int c2 = 0; c2 < 16; ++c2) {
        acc2a[c2].x = 0.f; acc2a[c2].y = 0.f;
        acc2b[c2].x = 0.f; acc2b[c2].y = 0.f;
    }
    float aa0 = 0.f, aa1 = 0.f, aa2 = 0.f;   // x-accumulator row0
    float ab0 = 0.f, ab1 = 0.f, ab2 = 0.f;   // x-accumulator row1
    float m0 = NEGF, m1 = NEGF, sum0 = 0.f, sum1 = 0.f;

    __syncthreads();     // staging complete

#pragma unroll 4
    for (int jj = 0; jj < CLEN; ++jj) {
        const int bit0 = (int)(mwa & 1ULL); mwa >>= 1;
        const int bit1 = (int)(mwb & 1ULL); mwb >>= 1;

        // K row: 4 x b128 = 16 u32 = 32 bf16; unpack once, use for both rows
        const uint4* kwp = (const uint4*)((const char*)kb_lds + (jj << 6));
        uint4 kA = kwp[0], kB = kwp[1], kC = kwp[2], kD = kwp[3];
        v2f kk[16];
        kk[0]  = bf2(kA.x); kk[1]  = bf2(kA.y); kk[2]  = bf2(kA.z); kk[3]  = bf2(kA.w);
        kk[4]  = bf2(kB.x); kk[5]  = bf2(kB.y); kk[6]  = bf2(kB.z); kk[7]  = bf2(kB.w);
        kk[8]  = bf2(kC.x); kk[9]  = bf2(kC.y); kk[10] = bf2(kC.z); kk[11] = bf2(kC.w);
        kk[12] = bf2(kD.x); kk[13] = bf2(kD.y); kk[14] = bf2(kD.z); kk[15] = bf2(kD.w);

        v2f Pa0 = {0.f,0.f}, Pa1 = {0.f,0.f}, Pb0 = {0.f,0.f}, Pb1 = {0.f,0.f};
#pragma unroll
        for (int c = 0; c < 8; ++c) {
            Pa0 = __builtin_elementwise_fma(q2a[2 * c],     kk[2 * c],     Pa0);
            Pa1 = __builtin_elementwise_fma(q2a[2 * c + 1], kk[2 * c + 1], Pa1);
            Pb0 = __builtin_elementwise_fma(q2b[2 * c],     kk[2 * c],     Pb0);
            Pb1 = __builtin_elementwise_fma(q2b[2 * c + 1], kk[2 * c + 1], Pb1);
        }
        v2f Sa = Pa0 + Pa1, Sb = Pb0 + Pb1;
        float dot0 = Sa.x + Sa.y, dot1 = Sb.x + Sb.y;

        float4 xj = *(const float4*)(x_lds + (jj << 2));
        float da0 = xa0 - xj.x, da1 = xa1 - xj.y, da2 = xa2 - xj.z;
        float db0 = xb0 - xj.x, db1 = xb1 - xj.y, db2 = xb2 - xj.z;
        float dista = fmaf(da2, da2, fmaf(da1, da1, da0 * da0));
        float distb = fmaf(db2, db2, fmaf(db1, db1, db0 * db0));
        float se0 = bit0 ? fmaf(dista, -LOG2E, dot0) : NEGF;
        float se1 = bit1 ? fmaf(distb, -LOG2E, dot1) : NEGF;

        if (__any(int(se0 - m0 > DEFER) | int(se1 - m1 > DEFER))) {
            float n0 = fmaxf(m0, se0), n1 = fmaxf(m1, se1);
            float al0 = exp2_fast(m0 - n0), al1 = exp2_fast(m1 - n1);
            m0 = n0; m1 = n1;
            sum0 *= al0; sum1 *= al1;
            v2f av0; av0.x = al0; av0.y = al0;
            v2f av1; av1.x = al1; av1.y = al1;
#pragma unroll
            for (int c2 = 0; c2 < 16; ++c2) { acc2a[c2] *= av0; acc2b[c2] *= av1; }
            aa0 *= al0; aa1 *= al0; aa2 *= al0;
            ab0 *= al1; ab1 *= al1; ab2 *= al1;
        }
        float p0 = exp2_fast(se0 - m0);
        float p1 = exp2_fast(se1 - m1);
        sum0 += p0; sum1 += p1;
        v2f pv0; pv0.x = p0; pv0.y = p0;
        v2f pv1; pv1.x = p1; pv1.y = p1;

        const uint4* vwp = (const uint4*)((const char*)vb_lds + (jj << 6));
        uint4 vA = vwp[0], vB = vwp[1], vC = vwp[2], vD = vwp[3];
        v2f vv[16];
        vv[0]  = bf2(vA.x); vv[1]  = bf2(vA.y); vv[2]  = bf2(vA.z); vv[3]  = bf2(vA.w);
        vv[4]  = bf2(vB.x); vv[5]  = bf2(vB.y); vv[6]  = bf2(vB.z); vv[7]  = bf2(vB.w);
        vv[8]  = bf2(vC.x); vv[9]  = bf2(vC.y); vv[10] = bf2(vC.z); vv[11] = bf2(vC.w);
        vv[12] = bf2(vD.x); vv[13] = bf2(vD.y); vv[14] = bf2(vD.z); vv[15] = bf2(vD.w);
#pragma unroll
        for (int c2 = 0; c2 < 16; ++c2) {
            acc2a[c2] = __builtin_elementwise_fma(pv0, vv[c2], acc2a[c2]);
            acc2b[c2] = __builtin_elementwise_fma(pv1, vv[c2], acc2b[c2]);
        }
        aa0 = fmaf(p0, xj.x, aa0); aa1 = fmaf(p0, xj.y, aa1); aa2 = fmaf(p0, xj.z, aa2);
        ab0 = fmaf(p1, xj.x, ab0); ab1 = fmaf(p1, xj.y, ab1); ab2 = fmaf(p1, xj.z, ab2);
    }

    // ---- write partials: stats [r][32], acc [c][r][36] contiguous per row
    pm[((size_t)r0 << 5) + cid] = m0;
    ps[((size_t)r0 << 5) + cid] = sum0;
    pm[((size_t)r1 << 5) + cid] = m1;
    ps[((size_t)r1 << 5) + cid] = sum1;
    {
        float* pb = pacc + ((size_t)cid * NRTOT + r0) * 36;
#pragma unroll
        for (int d4 = 0; d4 < 8; ++d4) {
            float4 st; st.x = acc2a[2*d4].x; st.y = acc2a[2*d4].y;
            st.z = acc2a[2*d4+1].x; st.w = acc2a[2*d4+1].y;
            *(float4*)(pb + (d4 << 2)) = st;
        }
        float4 st; st.x = aa0; st.y = aa1; st.z = aa2; st.w = 0.f;
        *(float4*)(pb + 32) = st;
    }
    {
        float* pb = pacc + ((size_t)cid * NRTOT + r1) * 36;
#pragma unroll
        for (int d4 = 0; d4 < 8; ++d4) {
            float4 st; st.x = acc2b[2*d4].x; st.y = acc2b[2*d4].y;
            st.z = acc2b[2*d4+1].x; st.w = acc2b[2*d4+1].y;
            *(float4*)(pb + (d4 << 2)) = st;
        }
        float4 st; st.x = ab0; st.y = ab1; st.z = ab2; st.w = 0.f;
        *(float4*)(pb + 32) = st;
    }
}

// ---------------------------------------------------------------- merge + epilogue + next-layer qkv
__global__ __launch_bounds__(256) void k_mergefin(const float* __restrict__ pm,
                                                  const float* __restrict__ ps,
                                                  const float* __restrict__ pacc,
                                                  float* __restrict__ hg,
                                                  const float* __restrict__ xin,
                                                  float* __restrict__ xout,
                                                  const float* __restrict__ Wo,
                                                  const float* __restrict__ W1,
                                                  const float* __restrict__ W2,
                                                  const float* __restrict__ csp,
                                                  const float* __restrict__ Wqn,
                                                  const float* __restrict__ Wkn,
                                                  const float* __restrict__ Wvn,
                                                  float* __restrict__ qout,
                                                  unsigned short* __restrict__ kbout,
                                                  unsigned short* __restrict__ vbout) {
    __shared__ float wo_s[1024];
    __shared__ float w1_s[2048];
    __shared__ float w2_s[2048];
    __shared__ float wq_s[1024];
    __shared__ float wk_s[1024];
    __shared__ float wv_s[1024];
    __shared__ float ad_s[4][40];
    __shared__ float h1_s[4][36];
    __shared__ float h2_s[4][36];
    __shared__ float f_s[4][64];

    const int t = threadIdx.x, w = t >> 6, lane = t & 63;
    for (int i = t; i < 1024; i += 256) wo_s[i] = Wo[i];
    for (int i = t; i < 2048; i += 256) { w1_s[i] = W1[i]; w2_s[i] = W2[i]; }
    if (Wqn) {
        for (int i = t; i < 1024; i += 256) {
            wq_s[i] = Wqn[i]; wk_s[i] = Wkn[i]; wv_s[i] = Wvn[i];
        }
    }
    __syncthreads();

    const int r = (blockIdx.x << 2) + w;

    // merge stats across 32 chunks ([r][32] layout -> coalesced per wave)
    float pmv = NEGF, psv = 0.f;
    if (lane < NCHUNK) { pmv = pm[((size_t)r << 5) + lane]; psv = ps[((size_t)r << 5) + lane]; }
    float m_g = pmv;
#pragma unroll
    for (int off = 1; off < 64; off <<= 1) m_g = fmaxf(m_g, __shfl_xor(m_g, off));
    float scv = (lane < NCHUNK) ? exp2_fast(pmv - m_g) : 0.f;
    float sg = scv * psv;
#pragma unroll
    for (int off = 1; off < 64; off <<= 1) sg += __shfl_xor(sg, off);
    const float rinv = 1.0f / sg;

    // merged accumulator, lane = d (pacc [c][r][36], lane-contiguous reads)
    const int dl = (lane < 36) ? lane : 0;
    float ad = 0.f;
#pragma unroll
    for (int c = 0; c < NCHUNK; ++c) {
        float scc = __shfl(scv, c);
        float pv = pacc[((size_t)c * NRTOT + r) * 36 + dl];
        ad = fmaf(scc, pv, ad);
    }
    if (lane < 35) ad_s[w][lane] = ad;

    // Wo matmul: lane&31 = col (both halves compute redundantly)
    const int col = lane & 31;
    float hv = 0.f;
#pragma unroll
    for (int d = 0; d < 32; ++d) hv = fmaf(ad_s[w][d], wo_s[(d << 5) + col], hv);
    float h1 = 0.f;
    if (lane < 32) { h1 = hg[(((size_t)r) << 5) + lane] + hv * rinv; h1_s[w][lane] = h1; }

    // FF up: lane = u (64)
    float f = 0.f;
#pragma unroll
    for (int d = 0; d < 32; ++d) f = fmaf(h1_s[w][d], w1_s[(d << 6) + lane], f);
    f = fmaxf(f, 0.f);
    f_s[w][lane] = f;

    // FF down + residual: lane<32 = col
    if (lane < 32) {
        float v2a = 0.f;
#pragma unroll
        for (int u = 0; u < 64; ++u) v2a = fmaf(f_s[w][u], w2_s[(u << 5) + lane], v2a);
        float hnew = h1 + v2a;
        hg[(((size_t)r) << 5) + lane] = hnew;
        h2_s[w][lane] = hnew;
    }

    // equivariant x update
    if (lane < 3) {
        float o  = ad_s[w][32 + lane] * rinv;
        float xi = xin[r * 3 + lane];
        xout[r * 3 + lane] = xi + csp[0] * (xi - o);
    }

    // fused next-layer qkv (lane<32 = output column); k/v emitted as bf16
    if (Wqn && lane < 32) {
        float aq = 0.f, ak = 0.f, av = 0.f;
#pragma unroll
        for (int d = 0; d < 32; ++d) {
            float hd = h2_s[w][d];
            aq = fmaf(hd, wq_s[(d << 5) + lane], aq);
            ak = fmaf(hd, wk_s[(d << 5) + lane], ak);
            av = fmaf(hd, wv_s[(d << 5) + lane], av);
        }
        qout[(((size_t)r) << 5) + lane]  = aq;
        kbout[(((size_t)r) << 5) + lane] = f2bf(ak);
        vbout[(((size_t)r) << 5) + lane] = f2bf(av);
    }
}

// ---------------------------------------------------------------- pooling stage 1 (parallel)
__global__ __launch_bounds__(256) void k_pool(const float* __restrict__ h,
                                              float* __restrict__ pool_ws) {
    const int b = blockIdx.x >> 5, sub = blockIdx.x & 31;
    const int t = threadIdx.x, c = t & 31, g = t >> 5;
    float s = 0.f;
#pragma unroll
    for (int i = 0; i < 8; ++i) {
        int row = (sub << 6) + (g << 3) + i;
        s += h[(((size_t)((b << 11) + row)) << 5) + c];
    }
    __shared__ float pool[8][32];
    pool[g][c] = s;
    __syncthreads();
    if (t < 32) {
        float ss = 0.f;
#pragma unroll
        for (int gg = 0; gg < 8; ++gg) ss += pool[gg][t];
        pool_ws[((b << 5) + sub) * 32 + t] = ss;
    }
}

// ---------------------------------------------------------------- head (tiny)
__global__ __launch_bounds__(256) void k_head(const float* __restrict__ pool_ws,
                                              const float* __restrict__ Wf1,
                                              const float* __restrict__ bf1,
                                              const float* __restrict__ Wf2,
                                              const float* __restrict__ bf2,
                                              float* __restrict__ out) {
    __shared__ float pooled[4][32];
    __shared__ float a1[4][16];
    const int t = threadIdx.x;
    if (t < 128) {
        int b = t >> 5, c = t & 31;
        float ss = 0.f;
#pragma unroll
        for (int sub = 0; sub < 32; ++sub) ss += pool_ws[((b << 5) + sub) * 32 + c];
        pooled[b][c] = ss * (1.0f / N_);
    }
    __syncthreads();
    if (t < 64) {
        int b = t >> 4, u = t & 15;
        float a = bf1[u];
#pragma unroll
        for (int d = 0; d < 32; ++d) a += pooled[b][d] * Wf1[(d << 4) + u];
        a1[b][u] = fmaxf(a, 0.f);
    }
    __syncthreads();
    if (t < 12) {
        int b = t / 3, o = t - b * 3;
        float v = bf2[o];
#pragma unroll
        for (int e = 0; e < 16; ++e) v += a1[b][e] * Wf2[e * 3 + o];
        out[b * 3 + o] = v;
    }
}

// ---------------------------------------------------------------- launch
extern "C" void kernel_launch(void* const* d_in, const int* in_sizes, int n_in,
                              void* d_out, int out_size, void* d_ws, size_t ws_size,
                              hipStream_t stream) {
    const float* feats = (const float*)d_in[0];
    const float* coors = (const float*)d_in[1];
    const int*   adj   = (const int*)d_in[2];
    const float* W_in  = (const float*)d_in[3];
    const float* Wq    = (const float*)d_in[4];
    const float* Wk    = (const float*)d_in[5];
    const float* Wv    = (const float*)d_in[6];
    const float* Wo    = (const float*)d_in[7];
    const float* W1    = (const float*)d_in[8];
    const float* W2    = (const float*)d_in[9];
    const float* csc   = (const float*)d_in[10];
    const float* Wf1   = (const float*)d_in[11];
    const float* bf1   = (const float*)d_in[12];
    const float* Wf2   = (const float*)d_in[13];
    const float* bf2   = (const float*)d_in[14];

    const size_t BNH = (size_t)4 * N_ * H_;   // 262144
    float* ws = (float*)d_ws;
    float* h  = ws;
    float* q  = ws + BNH;
    unsigned short* kb = (unsigned short*)(ws + 2 * BNH);   // BNH ushorts (512KB)
    unsigned short* vb = (unsigned short*)(ws + 3 * BNH);
    float* x0 = ws + 4 * BNH;                          // 24576 floats
    float* x1 = x0 + (size_t)4 * N_ * 3;
    unsigned long long* mask = (unsigned long long*)(x1 + (size_t)4 * N_ * 3);  // 262144 u64
    float* pm   = (float*)(mask + 262144);             // 262144
    float* ps   = pm + (size_t)NCHUNK * NRTOT;         // 262144
    float* pacc = ps + (size_t)NCHUNK * NRTOT;         // 32*8192*36 floats (37.7MB)
    float* pool_ws = pacc + (size_t)NCHUNK * NRTOT * 36;  // 4096 floats

    k_adjmask<<<65536, 256, 0, stream>>>(adj, mask);
    k_init_qkv<<<1024, 256, 0, stream>>>(feats, W_in, Wq, Wk, Wv, h, q, kb, vb);

    const float* xin[3]  = {coors, x0, x1};
    float*       xout[3] = {x0, x1, x0};
    for (int l = 0; l < 3; ++l) {
        k_attn<<<512, 256, 0, stream>>>(q, kb, vb, xin[l], mask, pm, ps, pacc);
        const bool last = (l == 2);
        k_mergefin<<<2048, 256, 0, stream>>>(pm, ps, pacc, h, xin[l], xout[l],
                                             Wo + l * 1024, W1 + l * 2048, W2 + l * 2048,
                                             csc + l,
                                             last ? nullptr : Wq + (l + 1) * 1024,
                                             last ? nullptr : Wk + (l + 1) * 1024,
                                             last ? nullptr : Wv + (l + 1) * 1024,
                                             q, kb, vb);
    }
    k_pool<<<128, 256, 0, stream>>>(h, pool_ws);
    k_head<<<1, 256, 0, stream>>>(pool_ws, Wf1, bf1, Wf2, bf2, (float*)d_out);
}